// Round 2
// baseline (3194.969 us; speedup 1.0000x reference)
//
#include <hip/hip_runtime.h>
#include <hip/hip_bf16.h>

// ---------------------------------------------------------------------------
// TAGConv (K=2) x2 + segment-max pool + linear head.
// bf16 intermediates (fp32 accumulate), commuted layer-2 propagation:
//   z2@W2 = X1@W2a + P(X1@W2b + P(X1@W2c)),  P = D^-1/2 A D^-1/2  (row-linear)
// Memory plan (~194 MB): CSR/misc ~15MB | CAT1 [N,384]bf16 (h|Ph|P^2h, later
// reused as B1 and X2) | X1 [N,256]bf16 | B2 [N,256]bf16.
// ---------------------------------------------------------------------------

typedef __hip_bfloat16 bf16;

__device__ inline float bf2f(bf16 v) { return __bfloat162float(v); }
__device__ inline bf16 f2bf(float v) { return __float2bfloat16(v); }

__global__ void hist_kernel(const int* __restrict__ dst, int* __restrict__ deg, int E) {
    int i = blockIdx.x * blockDim.x + threadIdx.x;
    if (i < E) atomicAdd(&deg[dst[i]], 1);
}

__global__ void norm_kernel(const int* __restrict__ deg, float* __restrict__ normv, int N) {
    int i = blockIdx.x * blockDim.x + threadIdx.x;
    if (i < N) {
        int d = deg[i];
        float fd = d < 1 ? 1.0f : (float)d;
        normv[i] = rsqrtf(fd);
    }
}

// Single-block chunked exclusive scan of deg -> rowptr (and cursor copy).
__global__ void scan_kernel(const int* __restrict__ deg, int* __restrict__ rowptr,
                            int* __restrict__ cursor, int n) {
    __shared__ int sdata[1024];
    __shared__ int s_running;
    int t = threadIdx.x;
    if (t == 0) s_running = 0;
    __syncthreads();
    for (int base = 0; base < n; base += 1024) {
        int v = (base + t < n) ? deg[base + t] : 0;
        sdata[t] = v;
        __syncthreads();
        for (int off = 1; off < 1024; off <<= 1) {
            int x = (t >= off) ? sdata[t - off] : 0;
            __syncthreads();
            sdata[t] += x;
            __syncthreads();
        }
        int incl = sdata[t];
        int run = s_running;
        if (base + t < n) {
            int excl = run + incl - v;
            rowptr[base + t] = excl;
            cursor[base + t] = excl;
        }
        __syncthreads();
        if (t == 1023) s_running = run + incl;
        __syncthreads();
    }
    if (t == 0) rowptr[n] = s_running;
}

__global__ void fill_kernel(const int* __restrict__ src, const int* __restrict__ dst,
                            int* __restrict__ cursor, int* __restrict__ colidx, int E) {
    int i = blockIdx.x * blockDim.x + threadIdx.x;
    if (i < E) {
        int d = dst[i];
        int pos = atomicAdd(&cursor[d], 1);
        colidx[pos] = src[i];
    }
}

// CAT1[:, 0:IN] = bf16(h)
__global__ void cast_kernel(const float* __restrict__ h, bf16* __restrict__ cat,
                            int total, int IN, int ldcat) {
    int i = blockIdx.x * blockDim.x + threadIdx.x;
    if (i < total) {
        int r = i / IN, c = i % IN;
        cat[(size_t)r * ldcat + c] = f2bf(h[i]);
    }
}

// out[i,t] = norm[i] * sum_{e in CSR row i} norm[col_e] * in[col_e, t]
// One block per node, one thread per feature (blockDim = d). fp32 accumulate.
__global__ void prop_kernel(const bf16* __restrict__ in, int ldin,
                            bf16* __restrict__ out, int ldout,
                            const int* __restrict__ rowptr, const int* __restrict__ colidx,
                            const float* __restrict__ normv, int N) {
    int i = blockIdx.x;
    int t = threadIdx.x;
    int s = rowptr[i], e = rowptr[i + 1];
    float acc = 0.f;
    for (int p = s; p < e; ++p) {
        int c = colidx[p];
        acc += normv[c] * bf2f(in[(size_t)c * ldin + t]);
    }
    out[(size_t)i * ldout + t] = f2bf(normv[i] * acc);
}

__device__ inline void unpack2(unsigned int u, float& a, float& b) {
    a = __uint_as_float(u << 16);
    b = __uint_as_float(u & 0xffff0000u);
}

// Cout = [relu]( A(bf16) @ B(fp32) [+ Cadd(bf16)] [+ bias] )  -> bf16
// A row-major [M x Kd] (lda), B row-major [Kd x Nn] (ldb=Nn), BN-wide blocks.
constexpr int BM = 128, BN = 64, BK = 16;
__global__ __launch_bounds__(256) void gemm_bf16(
    const bf16* __restrict__ A, int lda,
    const float* __restrict__ B, int ldb,
    const bf16* __restrict__ Cadd,      // nullable
    const float* __restrict__ bias,     // nullable
    bf16* __restrict__ Cout, int ldc,
    int M, int Kd, int relu) {
    __shared__ float As[BK][BM + 4];
    __shared__ float Bs[BK][BN];
    const int tid = threadIdx.x;
    const int tx = tid & 15;   // col group (x4)
    const int ty = tid >> 4;   // row group (x8)
    const int row0 = blockIdx.x * BM;
    const int col0 = blockIdx.y * BN;
    float acc[8][4] = {};
    for (int k0 = 0; k0 < Kd; k0 += BK) {
        // A tile: 128 rows x 16 bf16 cols. thread: r = tid>>1, half = tid&1,
        // loads 8 contiguous bf16 (16B, aligned: lda multiple of 8, k0 mult 16).
        {
            int r = tid >> 1, half = tid & 1;
            int gr = row0 + r;
            float f[8] = {};
            if (gr < M) {
                uint4 u = *(const uint4*)(A + (size_t)gr * lda + k0 + half * 8);
                unpack2(u.x, f[0], f[1]);
                unpack2(u.y, f[2], f[3]);
                unpack2(u.z, f[4], f[5]);
                unpack2(u.w, f[6], f[7]);
            }
            #pragma unroll
            for (int j = 0; j < 8; ++j) As[half * 8 + j][r] = f[j];
        }
        // B tile: 16 rows x 64 fp32 cols. thread: r = tid>>4, cg = tid&15.
        {
            int r = tid >> 4, cg = tid & 15;
            float4 v = *(const float4*)(B + (size_t)(k0 + r) * ldb + col0 + cg * 4);
            Bs[r][cg * 4 + 0] = v.x;
            Bs[r][cg * 4 + 1] = v.y;
            Bs[r][cg * 4 + 2] = v.z;
            Bs[r][cg * 4 + 3] = v.w;
        }
        __syncthreads();
        #pragma unroll
        for (int kk = 0; kk < BK; ++kk) {
            float a[8], b[4];
            #pragma unroll
            for (int i = 0; i < 8; ++i) a[i] = As[kk][ty * 8 + i];
            #pragma unroll
            for (int j = 0; j < 4; ++j) b[j] = Bs[kk][tx * 4 + j];
            #pragma unroll
            for (int i = 0; i < 8; ++i)
                #pragma unroll
                for (int j = 0; j < 4; ++j)
                    acc[i][j] += a[i] * b[j];
        }
        __syncthreads();
    }
    #pragma unroll
    for (int i = 0; i < 8; ++i) {
        int gr = row0 + ty * 8 + i;
        if (gr < M) {
            #pragma unroll
            for (int j = 0; j < 4; ++j) {
                int gc = col0 + tx * 4 + j;
                float v = acc[i][j];
                if (Cadd) v += bf2f(Cadd[(size_t)gr * ldc + gc]);
                if (bias) v += bias[gc];
                if (relu) v = fmaxf(v, 0.f);
                Cout[(size_t)gr * ldc + gc] = f2bf(v);
            }
        }
    }
}

// Segment max, sorted graph_ids; x >= 0 (post-relu) so int-punned atomicMax
// against 0-initialized pooled is exact. blockDim = HID.
__global__ void pool_kernel(const bf16* __restrict__ x, const int* __restrict__ gid,
                            float* __restrict__ pooled, int N, int HID) {
    int t = threadIdx.x;
    int n0 = blockIdx.x * 128;
    int n1 = n0 + 128 < N ? n0 + 128 : N;
    float cur = 0.f;
    int cg = gid[n0];
    for (int n = n0; n < n1; ++n) {
        int g = gid[n];
        if (g != cg) {
            atomicMax((int*)&pooled[(size_t)cg * HID + t], __float_as_int(cur));
            cg = g;
            cur = 0.f;
        }
        float v = bf2f(x[(size_t)n * HID + t]);
        cur = cur > v ? cur : v;
    }
    atomicMax((int*)&pooled[(size_t)cg * HID + t], __float_as_int(cur));
}

__global__ void head_kernel(const float* __restrict__ pooled, const float* __restrict__ Wc,
                            const float* __restrict__ bc, float* __restrict__ out,
                            int HID, int C) {
    __shared__ float row[256];
    int g = blockIdx.x;
    int t = threadIdx.x;
    if (t < HID) row[t] = pooled[(size_t)g * HID + t];
    __syncthreads();
    if (t < C) {
        float s = bc[t];
        for (int k = 0; k < HID; ++k) s += row[k] * Wc[(size_t)k * C + t];
        out[(size_t)g * C + t] = s;
    }
}

extern "C" void kernel_launch(void* const* d_in, const int* in_sizes, int n_in,
                              void* d_out, int out_size, void* d_ws, size_t ws_size,
                              hipStream_t stream) {
    const float* h  = (const float*)d_in[0];
    const int* src  = (const int*)d_in[1];
    const int* dst  = (const int*)d_in[2];
    const int* gid  = (const int*)d_in[3];
    const float* W1 = (const float*)d_in[4];
    const float* b1 = (const float*)d_in[5];
    const float* W2 = (const float*)d_in[6];
    const float* b2 = (const float*)d_in[7];
    const float* Wc = (const float*)d_in[8];
    const float* bc = (const float*)d_in[9];
    float* out = (float*)d_out;

    const int N   = in_sizes[3];          // 100000
    const int E   = in_sizes[1];          // 3200000
    const int IN  = in_sizes[0] / N;      // 128
    const int HID = in_sizes[5];          // 256
    const int C   = in_sizes[9];          // 10
    const int G   = out_size / C;         // 64
    const int CAT = 3 * IN;               // 384

    // --- workspace carve-out (256B-aligned chunks) ---
    char* wp = (char*)d_ws;
    auto alloc = [&](size_t bytes) {
        char* p = wp;
        wp += (bytes + 255) & ~(size_t)255;
        return p;
    };
    float* pooled = (float*)alloc((size_t)G * HID * sizeof(float));
    float* normv  = (float*)alloc((size_t)N * sizeof(float));
    int* deg      = (int*)alloc((size_t)N * sizeof(int));
    int* rowptr   = (int*)alloc((size_t)(N + 1) * sizeof(int));
    int* cursor   = (int*)alloc((size_t)N * sizeof(int));
    int* colidx   = (int*)alloc((size_t)E * sizeof(int));
    bf16* CAT1    = (bf16*)alloc((size_t)N * CAT * sizeof(bf16));   // [h|Ph|P2h]
    bf16* X1      = (bf16*)alloc((size_t)N * HID * sizeof(bf16));
    bf16* B2      = (bf16*)alloc((size_t)N * HID * sizeof(bf16));
    bf16* B1      = CAT1;  // alias: CAT1 dead after GEMM1; N*HID <= N*CAT

    // --- norm + CSR build ---
    hipMemsetAsync(deg, 0, (size_t)N * sizeof(int), stream);
    hist_kernel<<<(E + 255) / 256, 256, 0, stream>>>(dst, deg, E);
    norm_kernel<<<(N + 255) / 256, 256, 0, stream>>>(deg, normv, N);
    scan_kernel<<<1, 1024, 0, stream>>>(deg, rowptr, cursor, N);
    fill_kernel<<<(E + 255) / 256, 256, 0, stream>>>(src, dst, cursor, colidx, E);

    // --- layer 1: CAT1 = [bf16(h) | P h | P^2 h], then X1 = relu(CAT1@W1+b1) ---
    cast_kernel<<<((size_t)N * IN + 255) / 256, 256, 0, stream>>>(h, CAT1, N * IN, IN, CAT);
    prop_kernel<<<N, IN, 0, stream>>>(CAT1, CAT, CAT1 + IN, CAT, rowptr, colidx, normv, N);
    prop_kernel<<<N, IN, 0, stream>>>(CAT1 + IN, CAT, CAT1 + 2 * IN, CAT, rowptr, colidx, normv, N);
    {
        dim3 grid((N + BM - 1) / BM, HID / BN);
        gemm_bf16<<<grid, 256, 0, stream>>>(CAT1, CAT, W1, HID, nullptr, b1,
                                            X1, HID, N, CAT, 1);
    }

    // --- layer 2 (commuted): X2 = relu(X1@W2a + P(X1@W2b + P(X1@W2c)) + b2) ---
    {
        dim3 grid((N + BM - 1) / BM, HID / BN);
        // B1 = X1 @ W2c   (W2 rows [2*HID, 3*HID))
        gemm_bf16<<<grid, 256, 0, stream>>>(X1, HID, W2 + (size_t)2 * HID * HID, HID,
                                            nullptr, nullptr, B1, HID, N, HID, 0);
        // B2 = P(B1)
        prop_kernel<<<N, HID, 0, stream>>>(B1, HID, B2, HID, rowptr, colidx, normv, N);
        // B1 = X1 @ W2b + B2   (W2 rows [HID, 2*HID))
        gemm_bf16<<<grid, 256, 0, stream>>>(X1, HID, W2 + (size_t)HID * HID, HID,
                                            B2, nullptr, B1, HID, N, HID, 0);
        // B2 = P(B1)
        prop_kernel<<<N, HID, 0, stream>>>(B1, HID, B2, HID, rowptr, colidx, normv, N);
        // X2(=B1) = relu(X1 @ W2a + B2 + b2)
        gemm_bf16<<<grid, 256, 0, stream>>>(X1, HID, W2, HID,
                                            B2, b2, B1, HID, N, HID, 1);
    }

    // --- pool + head ---
    hipMemsetAsync(pooled, 0, (size_t)G * HID * sizeof(float), stream);
    pool_kernel<<<(N + 127) / 128, HID, 0, stream>>>(B1, gid, pooled, N, HID);
    head_kernel<<<G, HID, 0, stream>>>(pooled, Wc, bc, out, HID, C);
}

// Round 3
// 1614.996 us; speedup vs baseline: 1.9783x; 1.9783x over previous
//
#include <hip/hip_runtime.h>
#include <hip/hip_bf16.h>

// ---------------------------------------------------------------------------
// TAGConv (K=2) x2 + segment-max pool + linear head. bf16 intermediates,
// fp32 accumulate. Layer-2 commuted: z2@W2 = X1@W2a + P(X1@W2b + P(X1@W2c)).
// Round 3: wave-per-node prop with 8-deep edge unroll (MLP), MFMA bf16 GEMM
// (128x64 tile, global_load_lds staging, B panel LDS-resident), 3-kernel scan.
// ---------------------------------------------------------------------------

typedef unsigned short u16;
typedef unsigned int u32;

__device__ inline float u2f(u16 u) { return __uint_as_float(((u32)u) << 16); }
__device__ inline u16 f2u(float f) {
    __hip_bfloat16 b = __float2bfloat16(f);
    return *reinterpret_cast<u16*>(&b);
}

// ---------------------------- CSR build ------------------------------------

__global__ void hist_kernel(const int* __restrict__ dst, int* __restrict__ deg, int E) {
    int i = blockIdx.x * blockDim.x + threadIdx.x;
    if (i < E) atomicAdd(&deg[dst[i]], 1);
}

__global__ void norm_kernel(const int* __restrict__ deg, float* __restrict__ normv, int N) {
    int i = blockIdx.x * blockDim.x + threadIdx.x;
    if (i < N) {
        int d = deg[i];
        float fd = d < 1 ? 1.0f : (float)d;
        normv[i] = rsqrtf(fd);
    }
}

// Multi-block scan: scan1 (per-1024-chunk local excl scan + block sums),
// scan2 (single block excl scan of sums), scan3 (add offsets, write cursor).
__global__ void scan1_kernel(const int* __restrict__ deg, int* __restrict__ rowptr,
                             int* __restrict__ bsum, int n) {
    __shared__ int sd[1024];
    int t = threadIdx.x;
    int i = blockIdx.x * 1024 + t;
    int v = (i < n) ? deg[i] : 0;
    sd[t] = v;
    __syncthreads();
    for (int off = 1; off < 1024; off <<= 1) {
        int x = (t >= off) ? sd[t - off] : 0;
        __syncthreads();
        sd[t] += x;
        __syncthreads();
    }
    if (i < n) rowptr[i] = sd[t] - v;
    if (t == 1023) bsum[blockIdx.x] = sd[t];
}

__global__ void scan2_kernel(int* __restrict__ bsum, int nb) {
    __shared__ int sd[1024];
    int t = threadIdx.x;
    int v = (t < nb) ? bsum[t] : 0;
    sd[t] = v;
    __syncthreads();
    for (int off = 1; off < 1024; off <<= 1) {
        int x = (t >= off) ? sd[t - off] : 0;
        __syncthreads();
        sd[t] += x;
        __syncthreads();
    }
    if (t < nb) bsum[t] = sd[t] - v;
}

__global__ void scan3_kernel(int* __restrict__ rowptr, int* __restrict__ cursor,
                             const int* __restrict__ bsum, int n, int E) {
    int i = blockIdx.x * blockDim.x + threadIdx.x;
    if (i < n) {
        int r = rowptr[i] + bsum[i >> 10];
        rowptr[i] = r;
        cursor[i] = r;
    }
    if (i == 0) rowptr[n] = E;
}

__global__ void fill_kernel(const int* __restrict__ src, const int* __restrict__ dst,
                            int* __restrict__ cursor, int* __restrict__ colidx, int E) {
    int i = blockIdx.x * blockDim.x + threadIdx.x;
    if (i < E) {
        int d = dst[i];
        int pos = atomicAdd(&cursor[d], 1);
        colidx[pos] = src[i];
    }
}

// ------------------------------ cast h -------------------------------------

struct alignas(4) U2 { u16 v[2]; };
struct alignas(8) U4 { u16 v[4]; };
template <int VPT> struct VT;
template <> struct VT<2> { using T = U2; };
template <> struct VT<4> { using T = U4; };

// CAT1[:, 0:IN] = bf16(h), 4 floats per thread
__global__ void cast_kernel(const float* __restrict__ h, u16* __restrict__ cat,
                            int ngroups, int in4, int ldcat) {
    int i = blockIdx.x * blockDim.x + threadIdx.x;
    if (i < ngroups) {
        int r = i / in4, c4 = i % in4;
        float4 f = *(const float4*)(h + (size_t)i * 4);
        U4 o;
        o.v[0] = f2u(f.x); o.v[1] = f2u(f.y); o.v[2] = f2u(f.z); o.v[3] = f2u(f.w);
        *(U4*)(cat + (size_t)r * ldcat + c4 * 4) = o;
    }
}

// ----------------------------- propagation ---------------------------------
// out[i,:] = norm[i] * sum_{e in row i} norm[col_e] * in[col_e,:]
// One wave per node (4 nodes/block). Lane holds VPT features (vector load).
// Edge loop unrolled x8 for memory-level parallelism.

template <int VPT>
__global__ __launch_bounds__(256) void prop_kernel(
    const u16* __restrict__ in, int ldin,
    u16* __restrict__ out, int ldout,
    const int* __restrict__ rowptr, const int* __restrict__ colidx,
    const float* __restrict__ normv, int N) {
    using V = typename VT<VPT>::T;
    int node = blockIdx.x * 4 + (threadIdx.x >> 6);
    if (node >= N) return;
    int lane = threadIdx.x & 63;
    const u16* ip = in + lane * VPT;
    int s = rowptr[node], e = rowptr[node + 1];
    float acc[VPT];
    #pragma unroll
    for (int q = 0; q < VPT; ++q) acc[q] = 0.f;
    int p = s;
    for (; p + 8 <= e; p += 8) {
        int c[8];
        #pragma unroll
        for (int j = 0; j < 8; ++j) c[j] = colidx[p + j];
        V v[8];
        #pragma unroll
        for (int j = 0; j < 8; ++j) v[j] = *(const V*)(ip + (size_t)c[j] * ldin);
        float nm[8];
        #pragma unroll
        for (int j = 0; j < 8; ++j) nm[j] = normv[c[j]];
        #pragma unroll
        for (int j = 0; j < 8; ++j)
            #pragma unroll
            for (int q = 0; q < VPT; ++q)
                acc[q] += nm[j] * u2f(v[j].v[q]);
    }
    for (; p < e; ++p) {
        int c = colidx[p];
        float nm = normv[c];
        V v = *(const V*)(ip + (size_t)c * ldin);
        #pragma unroll
        for (int q = 0; q < VPT; ++q) acc[q] += nm * u2f(v.v[q]);
    }
    float nn = normv[node];
    V o;
    #pragma unroll
    for (int q = 0; q < VPT; ++q) o.v[q] = f2u(nn * acc[q]);
    *(V*)(out + (size_t)node * ldout + lane * VPT) = o;
}

// ------------------------------- MFMA GEMM ---------------------------------
// Cout[M x 256] = [relu]( A(bf16,[Mpad x lda]) @ Bt^T [+Cadd] [+bias] ) -> bf16
// Bt is [256 x K] bf16 row-major (pre-transposed weights, k-contiguous).
// Tile 128x64, BK=32, 4 waves (2x2), wave = 4x2 grid of 16x16x32 MFMAs.
// B panel (64 x K <= 48 KB) resident in LDS; A tile double-buffered via
// global_load_lds width-16.

typedef __attribute__((ext_vector_type(8))) short bf16x8f;
typedef __attribute__((ext_vector_type(4))) float f32x4;

__device__ inline void async16(const void* g, void* l) {
    __builtin_amdgcn_global_load_lds(
        (__attribute__((address_space(1))) void*)(g),
        (__attribute__((address_space(3))) void*)(l), 16, 0, 0);
}

constexpr int GBM = 128, GBN = 64, GBK = 32, KMAX = 384;

__device__ inline void stageA(const u16* __restrict__ A, int lda, int row0, int k0,
                              u16* dst, int tid) {
    // 128 rows x 32 bf16 cols = 8 KB = 512 x 16B chunks; 256 threads x 2.
    #pragma unroll
    for (int i = 0; i < 2; ++i) {
        int c = tid + i * 256;
        int row = c >> 2, seg = c & 3;
        async16(A + (size_t)(row0 + row) * lda + k0 + seg * 8, dst + c * 8);
    }
}

__global__ __launch_bounds__(256) void gemm_mfma(
    const u16* __restrict__ A, int lda,
    const u16* __restrict__ Bt,          // [256 x K]
    const u16* __restrict__ Cadd,        // nullable, [Mpad x 256]
    const float* __restrict__ bias,      // nullable, [256]
    u16* __restrict__ Cout,              // [Mpad x 256]
    int M, int K, int relu) {
    __shared__ u16 Ab[2][GBM * GBK];
    __shared__ u16 Bs[GBN * KMAX];
    const int tid = threadIdx.x;
    const int lane = tid & 63;
    const int wave = tid >> 6;
    const int wm = wave >> 1, wn = wave & 1;
    const int row0 = blockIdx.x * GBM;
    const int col0 = blockIdx.y * GBN;
    const int NOUT = 256;

    // stage B panel: contiguous 64*K bf16 from Bt + col0*K
    {
        const u16* src = Bt + (size_t)col0 * K;
        int chunks = GBN * K / 8;
        for (int c = tid; c < chunks; c += 256) async16(src + c * 8, &Bs[c * 8]);
    }
    stageA(A, lda, row0, 0, Ab[0], tid);
    __syncthreads();

    f32x4 acc[4][2];
    #pragma unroll
    for (int mi = 0; mi < 4; ++mi)
        #pragma unroll
        for (int ni = 0; ni < 2; ++ni) acc[mi][ni] = (f32x4)0.f;

    const int nk = K / GBK;
    const int mb = lane & 15;
    const int kk = (lane >> 4) * 8;
    for (int ks = 0; ks < nk; ++ks) {
        int cur = ks & 1;
        if (ks + 1 < nk) stageA(A, lda, row0, (ks + 1) * GBK, Ab[cur ^ 1], tid);
        bf16x8f a[4], b[2];
        #pragma unroll
        for (int mi = 0; mi < 4; ++mi)
            a[mi] = *(const bf16x8f*)&Ab[cur][(wm * 64 + mi * 16 + mb) * GBK + kk];
        #pragma unroll
        for (int ni = 0; ni < 2; ++ni)
            b[ni] = *(const bf16x8f*)&Bs[(size_t)(wn * 32 + ni * 16 + mb) * K + ks * GBK + kk];
        #pragma unroll
        for (int mi = 0; mi < 4; ++mi)
            #pragma unroll
            for (int ni = 0; ni < 2; ++ni)
                acc[mi][ni] = __builtin_amdgcn_mfma_f32_16x16x32_bf16(
                    a[mi], b[ni], acc[mi][ni], 0, 0, 0);
        __syncthreads();
    }

    // epilogue: C/D layout col = lane&15, row = (lane>>4)*4 + r
    #pragma unroll
    for (int mi = 0; mi < 4; ++mi) {
        #pragma unroll
        for (int r = 0; r < 4; ++r) {
            int row = row0 + wm * 64 + mi * 16 + (lane >> 4) * 4 + r;
            if (row < M) {
                #pragma unroll
                for (int ni = 0; ni < 2; ++ni) {
                    int col = col0 + wn * 32 + ni * 16 + (lane & 15);
                    float v = acc[mi][ni][r];
                    if (Cadd) v += u2f(Cadd[(size_t)row * NOUT + col]);
                    if (bias) v += bias[col];
                    if (relu) v = fmaxf(v, 0.f);
                    Cout[(size_t)row * NOUT + col] = f2u(v);
                }
            }
        }
    }
}

// Wt[n*K + k] = bf16(W[k*Nn + n])
__global__ void transpose_cast(const float* __restrict__ W, u16* __restrict__ Wt,
                               int K, int Nn) {
    int idx = blockIdx.x * blockDim.x + threadIdx.x;
    if (idx < K * Nn) {
        int n = idx / K, k = idx % K;
        Wt[idx] = f2u(W[(size_t)k * Nn + n]);
    }
}

// ------------------------------ pool + head --------------------------------

__global__ void pool_kernel(const u16* __restrict__ x, const int* __restrict__ gid,
                            float* __restrict__ pooled, int N, int HID) {
    int t = threadIdx.x;
    int n0 = blockIdx.x * 128;
    int n1 = n0 + 128 < N ? n0 + 128 : N;
    float cur = 0.f;
    int cg = gid[n0];
    for (int n = n0; n < n1; ++n) {
        int g = gid[n];
        if (g != cg) {
            atomicMax((int*)&pooled[(size_t)cg * HID + t], __float_as_int(cur));
            cg = g;
            cur = 0.f;
        }
        float v = u2f(x[(size_t)n * HID + t]);
        cur = cur > v ? cur : v;
    }
    atomicMax((int*)&pooled[(size_t)cg * HID + t], __float_as_int(cur));
}

__global__ void head_kernel(const float* __restrict__ pooled, const float* __restrict__ Wc,
                            const float* __restrict__ bc, float* __restrict__ out,
                            int HID, int C) {
    __shared__ float row[256];
    int g = blockIdx.x;
    int t = threadIdx.x;
    if (t < HID) row[t] = pooled[(size_t)g * HID + t];
    __syncthreads();
    if (t < C) {
        float s = bc[t];
        for (int k = 0; k < HID; ++k) s += row[k] * Wc[(size_t)k * C + t];
        out[(size_t)g * C + t] = s;
    }
}

// ------------------------------- launch ------------------------------------

extern "C" void kernel_launch(void* const* d_in, const int* in_sizes, int n_in,
                              void* d_out, int out_size, void* d_ws, size_t ws_size,
                              hipStream_t stream) {
    const float* h  = (const float*)d_in[0];
    const int* src  = (const int*)d_in[1];
    const int* dst  = (const int*)d_in[2];
    const int* gid  = (const int*)d_in[3];
    const float* W1 = (const float*)d_in[4];
    const float* b1 = (const float*)d_in[5];
    const float* W2 = (const float*)d_in[6];
    const float* b2 = (const float*)d_in[7];
    const float* Wc = (const float*)d_in[8];
    const float* bc = (const float*)d_in[9];
    float* out = (float*)d_out;

    const int N   = in_sizes[3];          // 100000
    const int E   = in_sizes[1];          // 3200000
    const int IN  = in_sizes[0] / N;      // 128
    const int HID = in_sizes[5];          // 256
    const int C   = in_sizes[9];          // 10
    const int G   = out_size / C;         // 64
    const int CAT = 3 * IN;               // 384
    const int Mpad = (N + 127) & ~127;    // 100096 (multiple of GBM)

    char* wp = (char*)d_ws;
    auto alloc = [&](size_t bytes) {
        char* p = wp;
        wp += (bytes + 255) & ~(size_t)255;
        return p;
    };
    float* pooled = (float*)alloc((size_t)G * HID * sizeof(float));
    float* normv  = (float*)alloc((size_t)N * sizeof(float));
    int* deg      = (int*)alloc((size_t)N * sizeof(int));
    int* rowptr   = (int*)alloc((size_t)(N + 1) * sizeof(int));
    int* cursor   = (int*)alloc((size_t)N * sizeof(int));
    int* bsum     = (int*)alloc(1024 * sizeof(int));
    int* colidx   = (int*)alloc((size_t)E * sizeof(int));
    u16* Wt1      = (u16*)alloc((size_t)CAT * HID * sizeof(u16));        // [256 x 384]
    u16* Wt2      = (u16*)alloc((size_t)3 * HID * HID * sizeof(u16));    // 3 x [256 x 256]
    u16* CAT1     = (u16*)alloc((size_t)Mpad * CAT * sizeof(u16));       // [h|Ph|P2h]
    u16* X1       = (u16*)alloc((size_t)Mpad * HID * sizeof(u16));
    u16* B2       = (u16*)alloc((size_t)Mpad * HID * sizeof(u16));
    u16* B1       = CAT1;   // alias: CAT1 dead after GEMM1

    // --- norm + CSR build ---
    hipMemsetAsync(deg, 0, (size_t)N * sizeof(int), stream);
    hist_kernel<<<(E + 255) / 256, 256, 0, stream>>>(dst, deg, E);
    norm_kernel<<<(N + 255) / 256, 256, 0, stream>>>(deg, normv, N);
    int nb = (N + 1023) / 1024;
    scan1_kernel<<<nb, 1024, 0, stream>>>(deg, rowptr, bsum, N);
    scan2_kernel<<<1, 1024, 0, stream>>>(bsum, nb);
    scan3_kernel<<<(N + 255) / 256, 256, 0, stream>>>(rowptr, cursor, bsum, N, E);
    fill_kernel<<<(E + 255) / 256, 256, 0, stream>>>(src, dst, cursor, colidx, E);

    // --- weight transpose + bf16 cast (small) ---
    transpose_cast<<<(CAT * HID + 255) / 256, 256, 0, stream>>>(W1, Wt1, CAT, HID);
    for (int s2 = 0; s2 < 3; ++s2)
        transpose_cast<<<(HID * HID + 255) / 256, 256, 0, stream>>>(
            W2 + (size_t)s2 * HID * HID, Wt2 + (size_t)s2 * HID * HID, HID, HID);

    // --- layer 1: CAT1 = [bf16(h) | P h | P^2 h]; X1 = relu(CAT1@W1+b1) ---
    {
        int ngroups = N * (IN / 4);
        cast_kernel<<<(ngroups + 255) / 256, 256, 0, stream>>>(h, CAT1, ngroups, IN / 4, CAT);
    }
    prop_kernel<2><<<(N + 3) / 4, 256, 0, stream>>>(CAT1, CAT, CAT1 + IN, CAT,
                                                    rowptr, colidx, normv, N);
    prop_kernel<2><<<(N + 3) / 4, 256, 0, stream>>>(CAT1 + IN, CAT, CAT1 + 2 * IN, CAT,
                                                    rowptr, colidx, normv, N);
    dim3 ggrid(Mpad / GBM, HID / GBN);
    gemm_mfma<<<ggrid, 256, 0, stream>>>(CAT1, CAT, Wt1, nullptr, b1, X1, N, CAT, 1);

    // --- layer 2 (commuted): X2 = relu(X1@W2a + P(X1@W2b + P(X1@W2c)) + b2) ---
    gemm_mfma<<<ggrid, 256, 0, stream>>>(X1, HID, Wt2 + (size_t)2 * HID * HID,
                                         nullptr, nullptr, B1, N, HID, 0);
    prop_kernel<4><<<(N + 3) / 4, 256, 0, stream>>>(B1, HID, B2, HID,
                                                    rowptr, colidx, normv, N);
    gemm_mfma<<<ggrid, 256, 0, stream>>>(X1, HID, Wt2 + (size_t)HID * HID,
                                         B2, nullptr, B1, N, HID, 0);
    prop_kernel<4><<<(N + 3) / 4, 256, 0, stream>>>(B1, HID, B2, HID,
                                                    rowptr, colidx, normv, N);
    gemm_mfma<<<ggrid, 256, 0, stream>>>(X1, HID, Wt2, B2, b2, B1, N, HID, 1);

    // --- pool + head ---
    hipMemsetAsync(pooled, 0, (size_t)G * HID * sizeof(float), stream);
    pool_kernel<<<(N + 127) / 128, HID, 0, stream>>>(B1, gid, pooled, N, HID);
    head_kernel<<<G, HID, 0, stream>>>(pooled, Wc, bc, out, HID, C);
}